// Round 23
// baseline (207.240 us; speedup 1.0000x reference)
//
#include <hip/hip_runtime.h>
#include <stdint.h>

typedef unsigned short u16;
typedef __attribute__((ext_vector_type(4))) unsigned short u16x4;
typedef __attribute__((ext_vector_type(8))) short bf16x8;
typedef __attribute__((ext_vector_type(4))) float f32x4;

#define PTOT 36864
#define WIMG 192

__device__ __forceinline__ float bf2f(u16 h) {
    union { uint32_t u; float f; } v; v.u = ((uint32_t)h) << 16; return v.f;
}
__device__ __forceinline__ u16 f2bf(float f) {
    union { float f; uint32_t u; } v; v.f = f;
    uint32_t u = v.u;
    return (u16)((u + 0x7FFFu + ((u >> 16) & 1u)) >> 16);
}

#define ASYNC_COPY16(gp, lp)                                                     \
    __builtin_amdgcn_global_load_lds(                                            \
        (const __attribute__((address_space(1))) void*)(gp),                     \
        (__attribute__((address_space(3))) void*)(lp), 16, 0, 0)

// ---------- transpose+convert both inputs: (b,256,P) f32 -> (b,P,256) bf16 ----
// R14 proven 64x64-tile version.  grid (576, 4, 4): z = tensor*2 + b.
__global__ __launch_bounds__(256) void k_transpose(const float* __restrict__ x,
                                                   const float* __restrict__ x2,
                                                   u16* __restrict__ xt,
                                                   u16* __restrict__ x2t) {
    __shared__ u16 tile[64][66];
    const int tx = threadIdx.x, ty = threadIdx.y;  // (64, 4)
    const int p0 = blockIdx.x * 64, c0 = blockIdx.y * 64;
    const int z = blockIdx.z, b = z & 1;
    const float* src = (z < 2 ? x : x2) + (size_t)b * 256 * PTOT;
    u16* dst = (z < 2 ? xt : x2t) + (size_t)b * PTOT * 256;
#pragma unroll
    for (int k = 0; k < 16; ++k) {
        const int c = c0 + ty + k * 4;
        tile[ty + k * 4][tx] = f2bf(src[(size_t)c * PTOT + p0 + tx]);
    }
    __syncthreads();
#pragma unroll
    for (int k = 0; k < 16; ++k) {
        const int p = p0 + ty + k * 4;
        dst[(size_t)p * 256 + c0 + tx] = tile[tx][ty + k * 4];
    }
}

// ---------- f32 -> bf16 for all three weight matrices (one launch) ----------
__global__ void k_f2bfAll(const float* __restrict__ w_qkv,
                          const float* __restrict__ w_qkv2,
                          const float* __restrict__ w_proj,
                          u16* __restrict__ dst) {
    const int i = blockIdx.x * 256 + threadIdx.x;  // 0..262143
    float v;
    if (i < 65536) v = w_qkv[i];
    else if (i < 196608) v = w_qkv2[i];
    else v = w_proj[i - 196608];
    dst[i] = f2bf(v);
}

// ---------- GEMM: C[b,row,p] = sum_c A[row,c] * Bt[b,p,c] + bias[row] ----------
// Proven R10/R14 design; grid (mb, nb, b) with mb FASTEST so consecutive
// blocks share one B-tile (immediate L2/L3 hits on the mb-pass re-reads).
template <bool OUT_F32>
__global__ __launch_bounds__(256) void k_gemm(const u16* __restrict__ A,
                                              const u16* __restrict__ Bt,
                                              void* __restrict__ Cout,
                                              const float* __restrict__ bias,
                                              int M) {
    __shared__ u16 As[128 * 32];
    __shared__ u16 Bs[128 * 32];
    const int tid = threadIdx.x;
    const int lane = tid & 63;
    const int wave = tid >> 6;
    const int wr = wave >> 1, wc = wave & 1;
    const int mb = blockIdx.x, nb = blockIdx.y, b = blockIdx.z;

    const u16* Ab = A + (size_t)(mb * 128) * 256;
    const u16* Bb = Bt + ((size_t)b * PTOT + (size_t)nb * 128) * 256;

    const int lrow = lane >> 2;
    const int lcol = (lane & 3) * 8;
    const int lr = lane & 15;
    const int lk = lane >> 4;

    f32x4 acc[4][4];
#pragma unroll
    for (int m = 0; m < 4; ++m)
#pragma unroll
        for (int n = 0; n < 4; ++n) acc[m][n] = (f32x4)0.f;

    for (int k0 = 0; k0 < 256; k0 += 32) {
        __syncthreads();
        const int i0 = wave * 2;
#pragma unroll
        for (int ii = 0; ii < 2; ++ii) {
            const int i = i0 + ii;
            ASYNC_COPY16(Ab + (size_t)(i * 16 + lrow) * 256 + k0 + lcol,
                         As + i * 16 * 32);
            ASYNC_COPY16(Bb + (size_t)(i * 16 + lrow) * 256 + k0 + lcol,
                         Bs + i * 16 * 32);
        }
        __syncthreads();
        const bf16x8* Asv = (const bf16x8*)As;
        const bf16x8* Bsv = (const bf16x8*)Bs;
        bf16x8 afr[4], bfr[4];
#pragma unroll
        for (int m = 0; m < 4; ++m)
            afr[m] = Asv[(wr * 64 + m * 16 + lr) * 4 + lk];
#pragma unroll
        for (int n = 0; n < 4; ++n)
            bfr[n] = Bsv[(wc * 64 + n * 16 + lr) * 4 + lk];
#pragma unroll
        for (int m = 0; m < 4; ++m)
#pragma unroll
            for (int n = 0; n < 4; ++n)
                acc[m][n] = __builtin_amdgcn_mfma_f32_16x16x32_bf16(
                    afr[m], bfr[n], acc[m][n], 0, 0, 0);
    }

    const int cr = (lane >> 4) * 4;
    const int cc = lane & 15;
#pragma unroll
    for (int m = 0; m < 4; ++m) {
#pragma unroll
        for (int j = 0; j < 4; ++j) {
            const int row = mb * 128 + wr * 64 + m * 16 + cr + j;
            const float bv = bias[row];
            const size_t rbase =
                ((size_t)b * M + row) * PTOT + (size_t)nb * 128 + wc * 64 + cc;
#pragma unroll
            for (int n = 0; n < 4; ++n) {
                const float v = acc[m][n][j] + bv;
                if (OUT_F32)
                    ((float*)Cout)[rbase + n * 16] = v;
                else
                    ((u16*)Cout)[rbase + n * 16] = f2bf(v);
            }
        }
    }
}

// ---------- dwconv3x3 -> MFMA-fragment layouts (rolling-4, prefetch dist 2) ---
// UNIFORM layout q/k/v: t[win][row8][ch32][px8].  XCD-aware remap (R22 win):
// xcd = id&7 owns contiguous 3-window (24-row) wy strips so halo rows dedupe
// inside one XCD's L2.
__global__ __launch_bounds__(256) void k_dwfrag(const u16* __restrict__ qpre,
                                                const u16* __restrict__ kvpre,
                                                const float* __restrict__ w_dw,
                                                const float* __restrict__ b_dw,
                                                const float* __restrict__ w_dw2,
                                                const float* __restrict__ b_dw2,
                                                u16* __restrict__ qw,
                                                u16* __restrict__ kw,
                                                u16* __restrict__ vw) {
    const int tid = threadIdx.x;
    const int c = tid >> 3, pxg = tid & 7;

    const int id = blockIdx.x + 72 * (blockIdx.y + 24 * blockIdx.z);  // 0..3455
    const int xcd = id & 7;
    const int slot = id >> 3;          // 0..431
    const int wy = xcd * 3 + slot % 3;
    const int rest = slot / 3;         // 0..143
    const int bx3 = rest % 3;
    const int slab = (rest / 3) % 24;
    const int b = rest / 72;

    const int path = slab >> 3, hh = slab & 7;
    const int ch = hh * 32 + c;

    const u16* src;
    const float* wp;
    float bias;
    u16* dst;
    if (path == 0) {
        src = qpre + ((size_t)b * 256 + ch) * PTOT;
        wp = w_dw + ch * 9; bias = b_dw[ch]; dst = qw;
    } else if (path == 1) {
        src = kvpre + ((size_t)b * 512 + ch) * PTOT;
        wp = w_dw2 + (256 + ch) * 9; bias = b_dw2[256 + ch]; dst = kw;
    } else {
        src = kvpre + ((size_t)b * 512 + 256 + ch) * PTOT;
        wp = w_dw2 + (512 + ch) * 9; bias = b_dw2[512 + ch]; dst = vw;
    }
    float w9[9];
#pragma unroll
    for (int i = 0; i < 9; ++i) w9[i] = wp[i];

    const int x0 = bx3 * 64 + pxg * 8;
    const size_t winbase =
        (((size_t)b * 8 + hh) * 576 + (size_t)wy * 24 + bx3 * 8 + pxg) * 2048;
    const int gy0 = wy * 8;

    float pr[4][10];
#define LOADROW(SLOT, YY)                                                        \
    do {                                                                         \
        const int yy_ = (YY);                                                    \
        if ((unsigned)yy_ >= (unsigned)WIMG) {                                   \
            _Pragma("unroll") for (int i_ = 0; i_ < 10; ++i_) pr[SLOT][i_] = 0.f;\
        } else {                                                                 \
            const u16* row_ = src + (size_t)yy_ * WIMG + x0;                     \
            const bf16x8 cv_ = *(const bf16x8*)row_;                             \
            pr[SLOT][0] = (x0 > 0) ? bf2f(row_[-1]) : 0.f;                       \
            pr[SLOT][9] = (x0 < 184) ? bf2f(row_[8]) : 0.f;                      \
            _Pragma("unroll") for (int i_ = 0; i_ < 8; ++i_)                     \
                pr[SLOT][i_ + 1] = bf2f((u16)cv_[i_]);                           \
        }                                                                        \
    } while (0)

    LOADROW(0, gy0 - 1);
    LOADROW(1, gy0);
    LOADROW(2, gy0 + 1);

#pragma unroll
    for (int y = 0; y < 8; ++y) {
        if (y < 7) LOADROW((y + 3) & 3, gy0 + y + 2);  // prefetch row y+2
        const int s0 = y & 3, s1 = (y + 1) & 3, s2 = (y + 2) & 3;  // static
        float acc[8];
#pragma unroll
        for (int i = 0; i < 8; ++i)
            acc[i] = bias
                   + w9[0] * pr[s0][i] + w9[1] * pr[s0][i + 1] + w9[2] * pr[s0][i + 2]
                   + w9[3] * pr[s1][i] + w9[4] * pr[s1][i + 1] + w9[5] * pr[s1][i + 2]
                   + w9[6] * pr[s2][i] + w9[7] * pr[s2][i + 1] + w9[8] * pr[s2][i + 2];
        bf16x8 ov;
#pragma unroll
        for (int i = 0; i < 8; ++i) ov[i] = (short)f2bf(acc[i]);
        *(bf16x8*)(dst + winbase + y * 256 + c * 8) = ov;
    }
#undef LOADROW
}

// ---------- windowed channel cross-attention from fragment layouts ----------
// grid (144, 8, 2); XCD remap MATCHED to dwfrag: wy-group g (= wy/3) lives on
// xcd g, so fragment tiles are read on the XCD whose L2 produced them.
__global__ __launch_bounds__(256) void k_attn(const u16* __restrict__ qw,
                                              const u16* __restrict__ kw,
                                              const u16* __restrict__ vw,
                                              const float* __restrict__ temp,
                                              u16* __restrict__ outt) {
    __shared__ __align__(16) char lds[28160];
    float* SS = (float*)lds;              // [w:1056][c:33][32] f32
    u16* P = (u16*)(lds + 16896);         // [w:1280][c:40][32] bf16
    float* IQ = (float*)(lds + 27136);    // [w][32]
    float* IK = (float*)(lds + 27648);

    const int tid = threadIdx.x;
    const int lane = tid & 63;
    const int wv = tid >> 6;  // wave id == local window

    // XCD-aware bijective remap: xcd g gets bx in [18g, 18g+18), all h, b.
    const int f = blockIdx.x + 144 * (blockIdx.y + 8 * blockIdx.z);  // 0..2303
    const int xcd = f & 7;
    const int slot = f >> 3;           // 0..287
    const int bx = 18 * xcd + slot % 18;
    const int rest = slot / 18;        // 0..15
    const int h = rest & 7;
    const int b = rest >> 3;

    const int win_lin = bx * 4 + wv;
    const int wy = win_lin / 24, wxc = win_lin % 24;
    const int lr = lane & 15, lk = lane >> 4;

    const size_t fb = (((size_t)b * 8 + h) * 576 + win_lin) * 2048;

    // ---- fragment loads ----
    bf16x8 aq[2][2], bk[2][2], vb[4];
#pragma unroll
    for (int kb = 0; kb < 2; ++kb) {
        const int roff = (kb * 4 + lk) * 256;
#pragma unroll
        for (int half = 0; half < 2; ++half) {
            const int coff = (half * 16 + lr) * 8;
            aq[kb][half] = *(const bf16x8*)(qw + fb + roff + coff);
            bk[kb][half] = *(const bf16x8*)(kw + fb + roff + coff);
        }
    }
#pragma unroll
    for (int ni = 0; ni < 4; ++ni) {
        const int n = ni * 16 + lr;
        const u16* vsrc = vw + fb + (size_t)(n >> 3) * 256 + (n & 7);
        bf16x8 v;
#pragma unroll
        for (int j = 0; j < 8; ++j) v[j] = (short)vsrc[(lk * 8 + j) * 8];
        vb[ni] = v;
    }

    // ---- l2-norms in-register ----
    {
        float sq0 = 0.f, sq1 = 0.f, sk0 = 0.f, sk1 = 0.f;
#pragma unroll
        for (int kb = 0; kb < 2; ++kb)
#pragma unroll
            for (int j = 0; j < 8; ++j) {
                float a0 = bf2f((u16)aq[kb][0][j]), a1 = bf2f((u16)aq[kb][1][j]);
                float k0 = bf2f((u16)bk[kb][0][j]), k1 = bf2f((u16)bk[kb][1][j]);
                sq0 += a0 * a0; sq1 += a1 * a1;
                sk0 += k0 * k0; sk1 += k1 * k1;
            }
        sq0 += __shfl_xor(sq0, 16); sq0 += __shfl_xor(sq0, 32);
        sq1 += __shfl_xor(sq1, 16); sq1 += __shfl_xor(sq1, 32);
        sk0 += __shfl_xor(sk0, 16); sk0 += __shfl_xor(sk0, 32);
        sk1 += __shfl_xor(sk1, 16); sk1 += __shfl_xor(sk1, 32);
        if (lk == 0) {
            IQ[wv * 32 + lr]      = 1.f / fmaxf(sqrtf(sq0), 1e-12f);
            IQ[wv * 32 + 16 + lr] = 1.f / fmaxf(sqrtf(sq1), 1e-12f);
            IK[wv * 32 + lr]      = 1.f / fmaxf(sqrtf(sk0), 1e-12f);
            IK[wv * 32 + 16 + lr] = 1.f / fmaxf(sqrtf(sk1), 1e-12f);
        }
    }

    // ---- QK^T ----
    {
        f32x4 s00 = (f32x4)0.f, s01 = (f32x4)0.f, s10 = (f32x4)0.f, s11 = (f32x4)0.f;
#pragma unroll
        for (int kb = 0; kb < 2; ++kb) {
            s00 = __builtin_amdgcn_mfma_f32_16x16x32_bf16(aq[kb][0], bk[kb][0], s00, 0, 0, 0);
            s01 = __builtin_amdgcn_mfma_f32_16x16x32_bf16(aq[kb][0], bk[kb][1], s01, 0, 0, 0);
            s10 = __builtin_amdgcn_mfma_f32_16x16x32_bf16(aq[kb][1], bk[kb][0], s10, 0, 0, 0);
            s11 = __builtin_amdgcn_mfma_f32_16x16x32_bf16(aq[kb][1], bk[kb][1], s11, 0, 0, 0);
        }
        float* srow = SS + wv * 1056;
        const int cr = lk * 4, cc = lr;
#pragma unroll
        for (int j = 0; j < 4; ++j) {
            srow[(cr + j) * 33 + cc] = s00[j];
            srow[(cr + j) * 33 + 16 + cc] = s01[j];
            srow[(16 + cr + j) * 33 + cc] = s10[j];
            srow[(16 + cr + j) * 33 + 16 + cc] = s11[j];
        }
    }
    __syncthreads();

    // ---- softmax: lane<32 of each wave owns one row ----
    if (lane < 32) {
        const float* srow = SS + wv * 1056 + lane * 33;
        const float* ik = IK + wv * 32;
        const float iq = IQ[wv * 32 + lane] * temp[h];
        float sv[32];
        float mx = -1e30f;
#pragma unroll
        for (int d = 0; d < 32; ++d) {
            sv[d] = srow[d] * ik[d] * iq;
            mx = fmaxf(mx, sv[d]);
        }
        float sum = 0.f;
#pragma unroll
        for (int d = 0; d < 32; ++d) {
            sv[d] = __expf(sv[d] - mx);
            sum += sv[d];
        }
        const float pinv = 1.f / sum;
        u16* prow = P + wv * 1280 + lane * 40;
#pragma unroll
        for (int ch = 0; ch < 4; ++ch) {
            bf16x8 pv;
#pragma unroll
            for (int i = 0; i < 8; ++i) pv[i] = (short)f2bf(sv[ch * 8 + i] * pinv);
            *(bf16x8*)(prow + ch * 8) = pv;
        }
    }
    __syncthreads();

    // ---- PV ----
    {
        bf16x8 pa0 = *(const bf16x8*)(P + wv * 1280 + lr * 40 + lk * 8);
        bf16x8 pa1 = *(const bf16x8*)(P + wv * 1280 + (16 + lr) * 40 + lk * 8);
        f32x4 o0[4], o1[4];
#pragma unroll
        for (int ni = 0; ni < 4; ++ni) { o0[ni] = (f32x4)0.f; o1[ni] = (f32x4)0.f; }
#pragma unroll
        for (int ni = 0; ni < 4; ++ni) {
            o0[ni] = __builtin_amdgcn_mfma_f32_16x16x32_bf16(pa0, vb[ni], o0[ni], 0, 0, 0);
            o1[ni] = __builtin_amdgcn_mfma_f32_16x16x32_bf16(pa1, vb[ni], o1[ni], 0, 0, 0);
        }
#pragma unroll
        for (int ni = 0; ni < 4; ++ni) {
            const int n = ni * 16 + lr;
            const size_t gp = (size_t)(wy * 8 + (n >> 3)) * WIMG + wxc * 8 + (n & 7);
            u16* op = outt + ((size_t)b * PTOT + gp) * 256 + h * 32;
            u16x4 pk0, pk1;
#pragma unroll
            for (int j = 0; j < 4; ++j) { pk0[j] = f2bf(o0[ni][j]); pk1[j] = f2bf(o1[ni][j]); }
            *(u16x4*)(op + lk * 4) = pk0;
            *(u16x4*)(op + 16 + lk * 4) = pk1;
        }
    }
}

extern "C" void kernel_launch(void* const* d_in, const int* in_sizes, int n_in,
                              void* d_out, int out_size, void* d_ws, size_t ws_size,
                              hipStream_t stream) {
    (void)in_sizes; (void)n_in; (void)out_size; (void)ws_size;
    const float* x      = (const float*)d_in[0];
    const float* x2     = (const float*)d_in[1];
    const float* w_qkv  = (const float*)d_in[2];
    const float* b_qkv  = (const float*)d_in[3];
    const float* w_dw   = (const float*)d_in[4];
    const float* b_dw   = (const float*)d_in[5];
    const float* w_qkv2 = (const float*)d_in[6];
    const float* b_qkv2 = (const float*)d_in[7];
    const float* w_dw2  = (const float*)d_in[8];
    const float* b_dw2  = (const float*)d_in[9];
    const float* temp   = (const float*)d_in[10];
    const float* w_proj = (const float*)d_in[11];
    const float* b_proj = (const float*)d_in[12];
    float* out = (float*)d_out;

    char* ws = (char*)d_ws;
    const size_t SZ_T  = (size_t)2 * PTOT * 256 * 2;  // 37.75 MB
    const size_t SZ_KV = (size_t)2 * PTOT * 512 * 2;  // 75.5 MB
    u16* xt     = (u16*)(ws);
    u16* x2t    = (u16*)(ws + SZ_T);
    u16* qpre   = (u16*)(ws + 2 * SZ_T);
    u16* kvpre  = (u16*)(ws + 3 * SZ_T);
    u16* vw     = (u16*)(ws + 3 * SZ_T + SZ_KV);
    u16* wq     = (u16*)(ws + 4 * SZ_T + SZ_KV);
    u16* wkv    = wq + 256 * 256;
    u16* wproj  = wkv + 512 * 256;
    u16* qw     = xt;    // xt dead after q-GEMM
    u16* kw     = x2t;   // x2t dead after kv-GEMM
    u16* attnt  = qpre;  // qpre dead after dwfrag

    const dim3 tb(64, 4);
    k_transpose<<<dim3(PTOT / 64, 4, 4), tb, 0, stream>>>(x, x2, xt, x2t);
    k_f2bfAll<<<262144 / 256, 256, 0, stream>>>(w_qkv, w_qkv2, w_proj, wq);

    // mb fastest: consecutive blocks share one B-tile
    k_gemm<false><<<dim3(4, PTOT / 128, 2), 256, 0, stream>>>(wkv, x2t, kvpre, b_qkv2 + 256, 512);
    k_gemm<false><<<dim3(2, PTOT / 128, 2), 256, 0, stream>>>(wq, xt, qpre, b_qkv, 256);

    k_dwfrag<<<dim3(72, 24, 2), 256, 0, stream>>>(qpre, kvpre, w_dw, b_dw,
                                                  w_dw2, b_dw2, qw, kw, vw);

    k_attn<<<dim3(144, 8, 2), 256, 0, stream>>>(qw, kw, vw, temp, attnt);

    k_gemm<true><<<dim3(2, PTOT / 128, 2), 256, 0, stream>>>(wproj, attnt, out, b_proj, 256);
}

// Round 24
// 200.367 us; speedup vs baseline: 1.0343x; 1.0343x over previous
//
#include <hip/hip_runtime.h>
#include <stdint.h>

typedef unsigned short u16;
typedef __attribute__((ext_vector_type(4))) unsigned short u16x4;
typedef __attribute__((ext_vector_type(8))) short bf16x8;
typedef __attribute__((ext_vector_type(4))) float f32x4;

#define PTOT 36864
#define WIMG 192

__device__ __forceinline__ float bf2f(u16 h) {
    union { uint32_t u; float f; } v; v.u = ((uint32_t)h) << 16; return v.f;
}
__device__ __forceinline__ u16 f2bf(float f) {
    union { float f; uint32_t u; } v; v.f = f;
    uint32_t u = v.u;
    return (u16)((u + 0x7FFFu + ((u >> 16) & 1u)) >> 16);
}

#define ASYNC_COPY16(gp, lp)                                                     \
    __builtin_amdgcn_global_load_lds(                                            \
        (const __attribute__((address_space(1))) void*)(gp),                     \
        (__attribute__((address_space(3))) void*)(lp), 16, 0, 0)

// ---------- transpose+convert both inputs: (b,256,P) f32 -> (b,P,256) bf16 ----
// R14 proven 64x64-tile version.  grid (576, 4, 4): z = tensor*2 + b.
__global__ __launch_bounds__(256) void k_transpose(const float* __restrict__ x,
                                                   const float* __restrict__ x2,
                                                   u16* __restrict__ xt,
                                                   u16* __restrict__ x2t) {
    __shared__ u16 tile[64][66];
    const int tx = threadIdx.x, ty = threadIdx.y;  // (64, 4)
    const int p0 = blockIdx.x * 64, c0 = blockIdx.y * 64;
    const int z = blockIdx.z, b = z & 1;
    const float* src = (z < 2 ? x : x2) + (size_t)b * 256 * PTOT;
    u16* dst = (z < 2 ? xt : x2t) + (size_t)b * PTOT * 256;
#pragma unroll
    for (int k = 0; k < 16; ++k) {
        const int c = c0 + ty + k * 4;
        tile[ty + k * 4][tx] = f2bf(src[(size_t)c * PTOT + p0 + tx]);
    }
    __syncthreads();
#pragma unroll
    for (int k = 0; k < 16; ++k) {
        const int p = p0 + ty + k * 4;
        dst[(size_t)p * 256 + c0 + tx] = tile[tx][ty + k * 4];
    }
}

// ---------- f32 -> bf16 for all three weight matrices (one launch) ----------
__global__ void k_f2bfAll(const float* __restrict__ w_qkv,
                          const float* __restrict__ w_qkv2,
                          const float* __restrict__ w_proj,
                          u16* __restrict__ dst) {
    const int i = blockIdx.x * 256 + threadIdx.x;  // 0..262143
    float v;
    if (i < 65536) v = w_qkv[i];
    else if (i < 196608) v = w_qkv2[i];
    else v = w_proj[i - 196608];
    dst[i] = f2bf(v);
}

// ---------- GEMM: C[b,row,p] = sum_c A[row,c] * Bt[b,p,c] + bias[row] ----------
// Proven R10/R14 design: 128x128 tile, both operands via global_load_lds.
template <bool OUT_F32>
__global__ __launch_bounds__(256) void k_gemm(const u16* __restrict__ A,
                                              const u16* __restrict__ Bt,
                                              void* __restrict__ Cout,
                                              const float* __restrict__ bias,
                                              int M) {
    __shared__ u16 As[128 * 32];
    __shared__ u16 Bs[128 * 32];
    const int tid = threadIdx.x;
    const int lane = tid & 63;
    const int wave = tid >> 6;
    const int wr = wave >> 1, wc = wave & 1;
    const int nb = blockIdx.x, mb = blockIdx.y, b = blockIdx.z;

    const u16* Ab = A + (size_t)(mb * 128) * 256;
    const u16* Bb = Bt + ((size_t)b * PTOT + (size_t)nb * 128) * 256;

    const int lrow = lane >> 2;
    const int lcol = (lane & 3) * 8;
    const int lr = lane & 15;
    const int lk = lane >> 4;

    f32x4 acc[4][4];
#pragma unroll
    for (int m = 0; m < 4; ++m)
#pragma unroll
        for (int n = 0; n < 4; ++n) acc[m][n] = (f32x4)0.f;

    for (int k0 = 0; k0 < 256; k0 += 32) {
        __syncthreads();
        const int i0 = wave * 2;
#pragma unroll
        for (int ii = 0; ii < 2; ++ii) {
            const int i = i0 + ii;
            ASYNC_COPY16(Ab + (size_t)(i * 16 + lrow) * 256 + k0 + lcol,
                         As + i * 16 * 32);
            ASYNC_COPY16(Bb + (size_t)(i * 16 + lrow) * 256 + k0 + lcol,
                         Bs + i * 16 * 32);
        }
        __syncthreads();
        const bf16x8* Asv = (const bf16x8*)As;
        const bf16x8* Bsv = (const bf16x8*)Bs;
        bf16x8 afr[4], bfr[4];
#pragma unroll
        for (int m = 0; m < 4; ++m)
            afr[m] = Asv[(wr * 64 + m * 16 + lr) * 4 + lk];
#pragma unroll
        for (int n = 0; n < 4; ++n)
            bfr[n] = Bsv[(wc * 64 + n * 16 + lr) * 4 + lk];
#pragma unroll
        for (int m = 0; m < 4; ++m)
#pragma unroll
            for (int n = 0; n < 4; ++n)
                acc[m][n] = __builtin_amdgcn_mfma_f32_16x16x32_bf16(
                    afr[m], bfr[n], acc[m][n], 0, 0, 0);
    }

    const int cr = (lane >> 4) * 4;
    const int cc = lane & 15;
#pragma unroll
    for (int m = 0; m < 4; ++m) {
#pragma unroll
        for (int j = 0; j < 4; ++j) {
            const int row = mb * 128 + wr * 64 + m * 16 + cr + j;
            const float bv = bias[row];
            const size_t rbase =
                ((size_t)b * M + row) * PTOT + (size_t)nb * 128 + wc * 64 + cc;
#pragma unroll
            for (int n = 0; n < 4; ++n) {
                const float v = acc[m][n][j] + bv;
                if (OUT_F32)
                    ((float*)Cout)[rbase + n * 16] = v;
                else
                    ((u16*)Cout)[rbase + n * 16] = f2bf(v);
            }
        }
    }
}

// ---------- dwconv3x3 -> MFMA-fragment layouts (rolling-4, prefetch dist 2) ---
// UNIFORM layout q/k/v: t[win][row8][ch32][px8].  XCD-aware remap (R22 win):
// xcd = id&7 owns contiguous 3-window (24-row) wy strips so halo rows dedupe
// inside one XCD's L2.
__global__ __launch_bounds__(256) void k_dwfrag(const u16* __restrict__ qpre,
                                                const u16* __restrict__ kvpre,
                                                const float* __restrict__ w_dw,
                                                const float* __restrict__ b_dw,
                                                const float* __restrict__ w_dw2,
                                                const float* __restrict__ b_dw2,
                                                u16* __restrict__ qw,
                                                u16* __restrict__ kw,
                                                u16* __restrict__ vw) {
    const int tid = threadIdx.x;
    const int c = tid >> 3, pxg = tid & 7;

    const int id = blockIdx.x + 72 * (blockIdx.y + 24 * blockIdx.z);  // 0..3455
    const int xcd = id & 7;
    const int slot = id >> 3;          // 0..431
    const int wy = xcd * 3 + slot % 3;
    const int rest = slot / 3;         // 0..143
    const int bx3 = rest % 3;
    const int slab = (rest / 3) % 24;
    const int b = rest / 72;

    const int path = slab >> 3, hh = slab & 7;
    const int ch = hh * 32 + c;

    const u16* src;
    const float* wp;
    float bias;
    u16* dst;
    if (path == 0) {
        src = qpre + ((size_t)b * 256 + ch) * PTOT;
        wp = w_dw + ch * 9; bias = b_dw[ch]; dst = qw;
    } else if (path == 1) {
        src = kvpre + ((size_t)b * 512 + ch) * PTOT;
        wp = w_dw2 + (256 + ch) * 9; bias = b_dw2[256 + ch]; dst = kw;
    } else {
        src = kvpre + ((size_t)b * 512 + 256 + ch) * PTOT;
        wp = w_dw2 + (512 + ch) * 9; bias = b_dw2[512 + ch]; dst = vw;
    }
    float w9[9];
#pragma unroll
    for (int i = 0; i < 9; ++i) w9[i] = wp[i];

    const int x0 = bx3 * 64 + pxg * 8;
    const size_t winbase =
        (((size_t)b * 8 + hh) * 576 + (size_t)wy * 24 + bx3 * 8 + pxg) * 2048;
    const int gy0 = wy * 8;

    float pr[4][10];
#define LOADROW(SLOT, YY)                                                        \
    do {                                                                         \
        const int yy_ = (YY);                                                    \
        if ((unsigned)yy_ >= (unsigned)WIMG) {                                   \
            _Pragma("unroll") for (int i_ = 0; i_ < 10; ++i_) pr[SLOT][i_] = 0.f;\
        } else {                                                                 \
            const u16* row_ = src + (size_t)yy_ * WIMG + x0;                     \
            const bf16x8 cv_ = *(const bf16x8*)row_;                             \
            pr[SLOT][0] = (x0 > 0) ? bf2f(row_[-1]) : 0.f;                       \
            pr[SLOT][9] = (x0 < 184) ? bf2f(row_[8]) : 0.f;                      \
            _Pragma("unroll") for (int i_ = 0; i_ < 8; ++i_)                     \
                pr[SLOT][i_ + 1] = bf2f((u16)cv_[i_]);                           \
        }                                                                        \
    } while (0)

    LOADROW(0, gy0 - 1);
    LOADROW(1, gy0);
    LOADROW(2, gy0 + 1);

#pragma unroll
    for (int y = 0; y < 8; ++y) {
        if (y < 7) LOADROW((y + 3) & 3, gy0 + y + 2);  // prefetch row y+2
        const int s0 = y & 3, s1 = (y + 1) & 3, s2 = (y + 2) & 3;  // static
        float acc[8];
#pragma unroll
        for (int i = 0; i < 8; ++i)
            acc[i] = bias
                   + w9[0] * pr[s0][i] + w9[1] * pr[s0][i + 1] + w9[2] * pr[s0][i + 2]
                   + w9[3] * pr[s1][i] + w9[4] * pr[s1][i + 1] + w9[5] * pr[s1][i + 2]
                   + w9[6] * pr[s2][i] + w9[7] * pr[s2][i + 1] + w9[8] * pr[s2][i + 2];
        bf16x8 ov;
#pragma unroll
        for (int i = 0; i < 8; ++i) ov[i] = (short)f2bf(acc[i]);
        *(bf16x8*)(dst + winbase + y * 256 + c * 8) = ov;
    }
#undef LOADROW
}

// ---------- windowed channel cross-attention from fragment layouts ----------
// grid (144, 8, 2), 256 threads.  LDS 27.5 KB.
__global__ __launch_bounds__(256) void k_attn(const u16* __restrict__ qw,
                                              const u16* __restrict__ kw,
                                              const u16* __restrict__ vw,
                                              const float* __restrict__ temp,
                                              u16* __restrict__ outt) {
    __shared__ __align__(16) char lds[28160];
    float* SS = (float*)lds;              // [w:1056][c:33][32] f32
    u16* P = (u16*)(lds + 16896);         // [w:1280][c:40][32] bf16
    float* IQ = (float*)(lds + 27136);    // [w][32]
    float* IK = (float*)(lds + 27648);

    const int tid = threadIdx.x;
    const int lane = tid & 63;
    const int wv = tid >> 6;  // wave id == local window
    const int h = blockIdx.y, b = blockIdx.z;
    const int win_lin = blockIdx.x * 4 + wv;
    const int wy = win_lin / 24, wxc = win_lin % 24;
    const int lr = lane & 15, lk = lane >> 4;

    const size_t fb = (((size_t)b * 8 + h) * 576 + win_lin) * 2048;

    // ---- fragment loads ----
    bf16x8 aq[2][2], bk[2][2], vb[4];
#pragma unroll
    for (int kb = 0; kb < 2; ++kb) {
        const int roff = (kb * 4 + lk) * 256;
#pragma unroll
        for (int half = 0; half < 2; ++half) {
            const int coff = (half * 16 + lr) * 8;
            aq[kb][half] = *(const bf16x8*)(qw + fb + roff + coff);
            bk[kb][half] = *(const bf16x8*)(kw + fb + roff + coff);
        }
    }
#pragma unroll
    for (int ni = 0; ni < 4; ++ni) {
        const int n = ni * 16 + lr;
        const u16* vsrc = vw + fb + (size_t)(n >> 3) * 256 + (n & 7);
        bf16x8 v;
#pragma unroll
        for (int j = 0; j < 8; ++j) v[j] = (short)vsrc[(lk * 8 + j) * 8];
        vb[ni] = v;
    }

    // ---- l2-norms in-register ----
    {
        float sq0 = 0.f, sq1 = 0.f, sk0 = 0.f, sk1 = 0.f;
#pragma unroll
        for (int kb = 0; kb < 2; ++kb)
#pragma unroll
            for (int j = 0; j < 8; ++j) {
                float a0 = bf2f((u16)aq[kb][0][j]), a1 = bf2f((u16)aq[kb][1][j]);
                float k0 = bf2f((u16)bk[kb][0][j]), k1 = bf2f((u16)bk[kb][1][j]);
                sq0 += a0 * a0; sq1 += a1 * a1;
                sk0 += k0 * k0; sk1 += k1 * k1;
            }
        sq0 += __shfl_xor(sq0, 16); sq0 += __shfl_xor(sq0, 32);
        sq1 += __shfl_xor(sq1, 16); sq1 += __shfl_xor(sq1, 32);
        sk0 += __shfl_xor(sk0, 16); sk0 += __shfl_xor(sk0, 32);
        sk1 += __shfl_xor(sk1, 16); sk1 += __shfl_xor(sk1, 32);
        if (lk == 0) {
            IQ[wv * 32 + lr]      = 1.f / fmaxf(sqrtf(sq0), 1e-12f);
            IQ[wv * 32 + 16 + lr] = 1.f / fmaxf(sqrtf(sq1), 1e-12f);
            IK[wv * 32 + lr]      = 1.f / fmaxf(sqrtf(sk0), 1e-12f);
            IK[wv * 32 + 16 + lr] = 1.f / fmaxf(sqrtf(sk1), 1e-12f);
        }
    }

    // ---- QK^T ----
    {
        f32x4 s00 = (f32x4)0.f, s01 = (f32x4)0.f, s10 = (f32x4)0.f, s11 = (f32x4)0.f;
#pragma unroll
        for (int kb = 0; kb < 2; ++kb) {
            s00 = __builtin_amdgcn_mfma_f32_16x16x32_bf16(aq[kb][0], bk[kb][0], s00, 0, 0, 0);
            s01 = __builtin_amdgcn_mfma_f32_16x16x32_bf16(aq[kb][0], bk[kb][1], s01, 0, 0, 0);
            s10 = __builtin_amdgcn_mfma_f32_16x16x32_bf16(aq[kb][1], bk[kb][0], s10, 0, 0, 0);
            s11 = __builtin_amdgcn_mfma_f32_16x16x32_bf16(aq[kb][1], bk[kb][1], s11, 0, 0, 0);
        }
        float* srow = SS + wv * 1056;
        const int cr = lk * 4, cc = lr;
#pragma unroll
        for (int j = 0; j < 4; ++j) {
            srow[(cr + j) * 33 + cc] = s00[j];
            srow[(cr + j) * 33 + 16 + cc] = s01[j];
            srow[(16 + cr + j) * 33 + cc] = s10[j];
            srow[(16 + cr + j) * 33 + 16 + cc] = s11[j];
        }
    }
    __syncthreads();

    // ---- softmax: lane<32 of each wave owns one row ----
    if (lane < 32) {
        const float* srow = SS + wv * 1056 + lane * 33;
        const float* ik = IK + wv * 32;
        const float iq = IQ[wv * 32 + lane] * temp[h];
        float sv[32];
        float mx = -1e30f;
#pragma unroll
        for (int d = 0; d < 32; ++d) {
            sv[d] = srow[d] * ik[d] * iq;
            mx = fmaxf(mx, sv[d]);
        }
        float sum = 0.f;
#pragma unroll
        for (int d = 0; d < 32; ++d) {
            sv[d] = __expf(sv[d] - mx);
            sum += sv[d];
        }
        const float pinv = 1.f / sum;
        u16* prow = P + wv * 1280 + lane * 40;
#pragma unroll
        for (int ch = 0; ch < 4; ++ch) {
            bf16x8 pv;
#pragma unroll
            for (int i = 0; i < 8; ++i) pv[i] = (short)f2bf(sv[ch * 8 + i] * pinv);
            *(bf16x8*)(prow + ch * 8) = pv;
        }
    }
    __syncthreads();

    // ---- PV ----
    {
        bf16x8 pa0 = *(const bf16x8*)(P + wv * 1280 + lr * 40 + lk * 8);
        bf16x8 pa1 = *(const bf16x8*)(P + wv * 1280 + (16 + lr) * 40 + lk * 8);
        f32x4 o0[4], o1[4];
#pragma unroll
        for (int ni = 0; ni < 4; ++ni) { o0[ni] = (f32x4)0.f; o1[ni] = (f32x4)0.f; }
#pragma unroll
        for (int ni = 0; ni < 4; ++ni) {
            o0[ni] = __builtin_amdgcn_mfma_f32_16x16x32_bf16(pa0, vb[ni], o0[ni], 0, 0, 0);
            o1[ni] = __builtin_amdgcn_mfma_f32_16x16x32_bf16(pa1, vb[ni], o1[ni], 0, 0, 0);
        }
#pragma unroll
        for (int ni = 0; ni < 4; ++ni) {
            const int n = ni * 16 + lr;
            const size_t gp = (size_t)(wy * 8 + (n >> 3)) * WIMG + wxc * 8 + (n & 7);
            u16* op = outt + ((size_t)b * PTOT + gp) * 256 + h * 32;
            u16x4 pk0, pk1;
#pragma unroll
            for (int j = 0; j < 4; ++j) { pk0[j] = f2bf(o0[ni][j]); pk1[j] = f2bf(o1[ni][j]); }
            *(u16x4*)(op + lk * 4) = pk0;
            *(u16x4*)(op + 16 + lk * 4) = pk1;
        }
    }
}

extern "C" void kernel_launch(void* const* d_in, const int* in_sizes, int n_in,
                              void* d_out, int out_size, void* d_ws, size_t ws_size,
                              hipStream_t stream) {
    (void)in_sizes; (void)n_in; (void)out_size; (void)ws_size;
    const float* x      = (const float*)d_in[0];
    const float* x2     = (const float*)d_in[1];
    const float* w_qkv  = (const float*)d_in[2];
    const float* b_qkv  = (const float*)d_in[3];
    const float* w_dw   = (const float*)d_in[4];
    const float* b_dw   = (const float*)d_in[5];
    const float* w_qkv2 = (const float*)d_in[6];
    const float* b_qkv2 = (const float*)d_in[7];
    const float* w_dw2  = (const float*)d_in[8];
    const float* b_dw2  = (const float*)d_in[9];
    const float* temp   = (const float*)d_in[10];
    const float* w_proj = (const float*)d_in[11];
    const float* b_proj = (const float*)d_in[12];
    float* out = (float*)d_out;

    char* ws = (char*)d_ws;
    const size_t SZ_T  = (size_t)2 * PTOT * 256 * 2;  // 37.75 MB
    const size_t SZ_KV = (size_t)2 * PTOT * 512 * 2;  // 75.5 MB
    u16* xt     = (u16*)(ws);
    u16* x2t    = (u16*)(ws + SZ_T);
    u16* qpre   = (u16*)(ws + 2 * SZ_T);
    u16* kvpre  = (u16*)(ws + 3 * SZ_T);
    u16* vw     = (u16*)(ws + 3 * SZ_T + SZ_KV);
    u16* wq     = (u16*)(ws + 4 * SZ_T + SZ_KV);
    u16* wkv    = wq + 256 * 256;
    u16* wproj  = wkv + 512 * 256;
    u16* qw     = xt;    // xt dead after q-GEMM
    u16* kw     = x2t;   // x2t dead after kv-GEMM
    u16* attnt  = qpre;  // qpre dead after dwfrag

    const dim3 tb(64, 4);
    k_transpose<<<dim3(PTOT / 64, 4, 4), tb, 0, stream>>>(x, x2, xt, x2t);
    k_f2bfAll<<<262144 / 256, 256, 0, stream>>>(w_qkv, w_qkv2, w_proj, wq);

    k_gemm<false><<<dim3(PTOT / 128, 4, 2), 256, 0, stream>>>(wkv, x2t, kvpre, b_qkv2 + 256, 512);
    k_gemm<false><<<dim3(PTOT / 128, 2, 2), 256, 0, stream>>>(wq, xt, qpre, b_qkv, 256);

    k_dwfrag<<<dim3(72, 24, 2), 256, 0, stream>>>(qpre, kvpre, w_dw, b_dw,
                                                  w_dw2, b_dw2, qw, kw, vw);

    k_attn<<<dim3(144, 8, 2), 256, 0, stream>>>(qw, kw, vw, temp, attnt);

    k_gemm<true><<<dim3(PTOT / 128, 2, 2), 256, 0, stream>>>(wproj, attnt, out, b_proj, 256);
}